// Round 2
// baseline (201.170 us; speedup 1.0000x reference)
//
#include <hip/hip_runtime.h>
#include <hip/hip_bf16.h>

// MaskedAttention: out = softmax(tril(q k^T)) v, q/k/v = x @ W{q,k,v}
// B=8 T=2048 D=1024 H=64, fp32 in/out, no 1/sqrt(H) scaling.
//
// Precision plan: q,k projections and QK^T use hi/lo bf16 splitting
// (3-MFMA "bf16x3") so logits are ~fp32-accurate; V/P plain bf16.

typedef __bf16 bf16x8 __attribute__((ext_vector_type(8)));
typedef float f32x4 __attribute__((ext_vector_type(4)));

#define MFMA16(a, b, c) __builtin_amdgcn_mfma_f32_16x16x32_bf16((a), (b), (c), 0, 0, 0)

static constexpr int BB = 8;
static constexpr int TT = 2048;
static constexpr int DD = 1024;
static constexpr int HH = 64;
static constexpr int NROW = BB * TT;       // 16384
static constexpr int WELEM = DD * HH;      // 65536 per matrix

__device__ __forceinline__ float rmax16(float v) {
#pragma unroll
  for (int m = 1; m < 16; m <<= 1) v = fmaxf(v, __shfl_xor(v, m, 64));
  return v;
}
__device__ __forceinline__ float rsum16(float v) {
#pragma unroll
  for (int m = 1; m < 16; m <<= 1) v += __shfl_xor(v, m, 64);
  return v;
}

// ---------------------------------------------------------------- W prep ---
// W [1024][64] fp32 -> Wt hi/lo [3][64][1024] bf16 (transposed, split)
__global__ __launch_bounds__(256) void wprep_kernel(
    const float* __restrict__ Wq, const float* __restrict__ Wk,
    const float* __restrict__ Wv, __bf16* __restrict__ WtHi,
    __bf16* __restrict__ WtLo) {
  int tid = blockIdx.x * 256 + threadIdx.x;
  if (tid >= 3 * WELEM) return;
  int m = tid / WELEM;
  int rem = tid - m * WELEM;
  int d = rem >> 6;
  int h = rem & 63;
  const float* W = (m == 0) ? Wq : ((m == 1) ? Wk : Wv);
  float v = W[d * 64 + h];
  __bf16 hi = (__bf16)v;
  float lo = v - (float)hi;
  size_t o = (size_t)m * WELEM + (size_t)h * 1024 + d;
  WtHi[o] = hi;
  WtLo[o] = (__bf16)lo;
}

// ------------------------------------------------------------ projection ---
// Fused x->bf16(hi/lo) conversion + GEMM. One block (4 waves) per 16-row
// tile; wave w owns column group c=w (16 cols). 4096 waves total = 4/SIMD
// (was 1/SIMD with the 4-tiles-per-block layout -> latency-bound, 104 us).
// q,k: 3-MFMA split (accurate); v: hi-only. Writes qh/ql/kh/kl [16384][64],
// vt [8][64][2048] (transposed for PV B-fragments).
__global__ __launch_bounds__(256) void proj_kernel(
    const float* __restrict__ x, const __bf16* __restrict__ WtHi,
    const __bf16* __restrict__ WtLo, __bf16* __restrict__ qh,
    __bf16* __restrict__ ql, __bf16* __restrict__ kh,
    __bf16* __restrict__ kl, __bf16* __restrict__ vt) {
  const int w = threadIdx.x >> 6, l = threadIdx.x & 63;
  const int lr = l & 15, lg = l >> 4;
  const int r0 = blockIdx.x * 16;
  const int c = w;  // column group (16 cols) owned by this wave

  const float* xp = x + (size_t)(r0 + lr) * DD + lg * 8;
  const __bf16* wq_h = WtHi;
  const __bf16* wk_h = WtHi + WELEM;
  const __bf16* wv_h = WtHi + 2 * WELEM;
  const __bf16* wq_l = WtLo;
  const __bf16* wk_l = WtLo + WELEM;

  f32x4 aq = {0.f, 0.f, 0.f, 0.f};
  f32x4 ak = {0.f, 0.f, 0.f, 0.f};
  f32x4 av = {0.f, 0.f, 0.f, 0.f};

#pragma unroll 2
  for (int d0 = 0; d0 < DD; d0 += 32) {
    const float4 xa = *(const float4*)(xp + d0);
    const float4 xb = *(const float4*)(xp + d0 + 4);
    float xs[8] = {xa.x, xa.y, xa.z, xa.w, xb.x, xb.y, xb.z, xb.w};
    bf16x8 ah, al;
#pragma unroll
    for (int j = 0; j < 8; ++j) {
      __bf16 h = (__bf16)xs[j];
      ah[j] = h;
      al[j] = (__bf16)(xs[j] - (float)h);
    }
    const int wo = (c * 16 + lr) * 1024 + d0 + lg * 8;
    bf16x8 bqh = *(const bf16x8*)(wq_h + wo);
    bf16x8 bql = *(const bf16x8*)(wq_l + wo);
    bf16x8 bkh = *(const bf16x8*)(wk_h + wo);
    bf16x8 bkl = *(const bf16x8*)(wk_l + wo);
    bf16x8 bvh = *(const bf16x8*)(wv_h + wo);
    aq = MFMA16(ah, bqh, aq);
    aq = MFMA16(ah, bql, aq);
    aq = MFMA16(al, bqh, aq);
    ak = MFMA16(ah, bkh, ak);
    ak = MFMA16(ah, bkl, ak);
    ak = MFMA16(al, bkh, ak);
    av = MFMA16(ah, bvh, av);
  }

#pragma unroll
  for (int i = 0; i < 4; ++i) {
    const int row = r0 + lg * 4 + i;  // C-layout: row=(lane>>4)*4+reg
    const int col = c * 16 + lr;      //           col=lane&15
    const size_t oq = (size_t)row * 64 + col;
    float qv = aq[i];
    __bf16 qhi = (__bf16)qv;
    qh[oq] = qhi;
    ql[oq] = (__bf16)(qv - (float)qhi);
    float kv = ak[i];
    __bf16 khi = (__bf16)kv;
    kh[oq] = khi;
    kl[oq] = (__bf16)(kv - (float)khi);
    const int bb = row >> 11, tt = row & 2047;
    vt[((size_t)bb * 64 + col) * 2048 + tt] = (__bf16)av[i];
  }
}

// -------------------------------------------------------------- attention ---
// Split-K flash. One block (4 waves) per 16-row q-tile; waves stride over
// 32-key tiles with private online-softmax state, then LSE-merge via LDS.
// 32-key tiles: QK^T = 3-term split (6 MFMA), fp32 online softmax via 16-lane
// shuffles, P staged bf16 in padded LDS (80B rows), PV = 4 MFMA.
__global__ __launch_bounds__(256) void attn_kernel(
    const __bf16* __restrict__ qh, const __bf16* __restrict__ ql,
    const __bf16* __restrict__ kh, const __bf16* __restrict__ kl,
    const __bf16* __restrict__ vt, float* __restrict__ out) {
  __shared__ __bf16 P[4][16][40];   // 40-col pad: 80B rows -> conflict-free b128
  __shared__ float Sm[4][16];       // per-wave row maxes
  __shared__ float Sl[4][16];       // per-wave row sums
  __shared__ float OB[4][16][68];   // per-wave scaled O (68 pad: <=2-way, free)
  __shared__ float Dinv[16];        // 1/denom per row
  const int w = threadIdx.x >> 6, l = threadIdx.x & 63;
  const int lr = l & 15, lg = l >> 4;
  const int b = blockIdx.y;
  const int qt = 127 - blockIdx.x;  // heavy tiles first (tail shrink)
  const int q0 = qt * 16;
  const float NEG = -__builtin_inff();

  const size_t qb = ((size_t)b * TT + q0 + lr) * 64 + lg * 8;
  const bf16x8 fqh0 = *(const bf16x8*)(qh + qb);
  const bf16x8 fqh1 = *(const bf16x8*)(qh + qb + 32);
  const bf16x8 fql0 = *(const bf16x8*)(ql + qb);
  const bf16x8 fql1 = *(const bf16x8*)(ql + qb + 32);

  f32x4 o0 = {0.f, 0.f, 0.f, 0.f}, o1 = o0, o2 = o0, o3 = o0;
  float m[4] = {NEG, NEG, NEG, NEG};
  float su[4] = {0.f, 0.f, 0.f, 0.f};
  const int nkt = (q0 + 47) >> 5;  // ceil((q0+16)/32)

#pragma unroll 1
  for (int kt = w; kt < nkt; kt += 4) {
    const int j0 = kt * 32;
    const f32x4 z = {0.f, 0.f, 0.f, 0.f};
    f32x4 sa, sb = {NEG, NEG, NEG, NEG};
    {
      const size_t kb = ((size_t)b * TT + j0 + lr) * 64 + lg * 8;
      const bf16x8 fk0 = *(const bf16x8*)(kh + kb);
      const bf16x8 fk1 = *(const bf16x8*)(kh + kb + 32);
      const bf16x8 fl0 = *(const bf16x8*)(kl + kb);
      const bf16x8 fl1 = *(const bf16x8*)(kl + kb + 32);
      f32x4 c0 = MFMA16(fqh1, fk1, MFMA16(fqh0, fk0, z));
      f32x4 c1 = MFMA16(fqh1, fl1, MFMA16(fqh0, fl0, z));
      f32x4 c2 = MFMA16(fql1, fk1, MFMA16(fql0, fk0, z));
      sa = c0 + c1 + c2;
    }
    const bool haveB = (j0 + 16) <= (q0 + 15);
    if (haveB) {
      const size_t kb = ((size_t)b * TT + j0 + 16 + lr) * 64 + lg * 8;
      const bf16x8 fk0 = *(const bf16x8*)(kh + kb);
      const bf16x8 fk1 = *(const bf16x8*)(kh + kb + 32);
      const bf16x8 fl0 = *(const bf16x8*)(kl + kb);
      const bf16x8 fl1 = *(const bf16x8*)(kl + kb + 32);
      f32x4 c0 = MFMA16(fqh1, fk1, MFMA16(fqh0, fk0, z));
      f32x4 c1 = MFMA16(fqh1, fl1, MFMA16(fqh0, fl0, z));
      f32x4 c2 = MFMA16(fql1, fk1, MFMA16(fql0, fk0, z));
      sb = c0 + c1 + c2;
    }
    // causal mask (row = q0 + lg*4 + i, key = j0 [+16] + lr)
#pragma unroll
    for (int i = 0; i < 4; ++i) {
      const int rowg = q0 + lg * 4 + i;
      if (j0 + lr > rowg) sa[i] = NEG;
      if (j0 + 16 + lr > rowg) sb[i] = NEG;
    }
    // online softmax update + stage P in LDS
#pragma unroll
    for (int i = 0; i < 4; ++i) {
      float t = rmax16(fmaxf(sa[i], sb[i]));
      const float mn = fmaxf(m[i], t);
      const float sc = __expf(m[i] - mn);
      m[i] = mn;
      const float pa = __expf(sa[i] - mn);
      const float pb = __expf(sb[i] - mn);
      su[i] = su[i] * sc + rsum16(pa + pb);
      o0[i] *= sc; o1[i] *= sc; o2[i] *= sc; o3[i] *= sc;
      P[w][lg * 4 + i][lr] = (__bf16)pa;
      P[w][lg * 4 + i][16 + lr] = (__bf16)pb;
    }
    // PV: A-frag of P (same-wave LDS ops are in-order; compiler adds waits)
    const bf16x8 pf = *(const bf16x8*)(&P[w][lr][lg * 8]);
    const size_t vb = ((size_t)b * 64 + lr) * 2048 + j0 + lg * 8;
    o0 = MFMA16(pf, *(const bf16x8*)(vt + vb), o0);
    o1 = MFMA16(pf, *(const bf16x8*)(vt + vb + (size_t)16 * 2048), o1);
    o2 = MFMA16(pf, *(const bf16x8*)(vt + vb + (size_t)32 * 2048), o2);
    o3 = MFMA16(pf, *(const bf16x8*)(vt + vb + (size_t)48 * 2048), o3);
  }

  // ------- LSE merge of the 4 per-wave partials -------
  if (lr == 0) {
#pragma unroll
    for (int i = 0; i < 4; ++i) {
      Sm[w][lg * 4 + i] = m[i];
      Sl[w][lg * 4 + i] = su[i];
    }
  }
  __syncthreads();
#pragma unroll
  for (int i = 0; i < 4; ++i) {
    const int row = lg * 4 + i;
    float M = fmaxf(fmaxf(Sm[0][row], Sm[1][row]),
                    fmaxf(Sm[2][row], Sm[3][row]));
    const float sc = __expf(m[i] - M);  // 0 if this wave was idle (m=-inf)
    OB[w][row][lr] = o0[i] * sc;
    OB[w][row][16 + lr] = o1[i] * sc;
    OB[w][row][32 + lr] = o2[i] * sc;
    OB[w][row][48 + lr] = o3[i] * sc;
    if (w == 0 && lr == 0) {
      float denom = 0.f;
#pragma unroll
      for (int w2 = 0; w2 < 4; ++w2)
        denom += Sl[w2][row] * __expf(Sm[w2][row] - M);
      Dinv[row] = 1.0f / denom;
    }
  }
  __syncthreads();
  const int t = threadIdx.x;
#pragma unroll
  for (int k2 = 0; k2 < 4; ++k2) {
    const int e = t + 256 * k2;
    const int row = e >> 6, col = e & 63;
    const float s = OB[0][row][col] + OB[1][row][col] + OB[2][row][col] +
                    OB[3][row][col];
    out[((size_t)b * TT + q0 + row) * 64 + col] = s * Dinv[row];
  }
}

// ------------------------------------------------------------------ launch ---
extern "C" void kernel_launch(void* const* d_in, const int* in_sizes, int n_in,
                              void* d_out, int out_size, void* d_ws,
                              size_t ws_size, hipStream_t stream) {
  const float* x = (const float*)d_in[0];
  const float* Wq = (const float*)d_in[1];
  const float* Wk = (const float*)d_in[2];
  const float* Wv = (const float*)d_in[3];
  float* out = (float*)d_out;
  char* ws = (char*)d_ws;

  size_t off = 0;
  __bf16* WtHi = (__bf16*)(ws + off); off += (size_t)3 * WELEM * 2;
  __bf16* WtLo = (__bf16*)(ws + off); off += (size_t)3 * WELEM * 2;
  __bf16* qh = (__bf16*)(ws + off); off += (size_t)NROW * 64 * 2;
  __bf16* ql = (__bf16*)(ws + off); off += (size_t)NROW * 64 * 2;
  __bf16* kh = (__bf16*)(ws + off); off += (size_t)NROW * 64 * 2;
  __bf16* kl = (__bf16*)(ws + off); off += (size_t)NROW * 64 * 2;
  __bf16* vt = (__bf16*)(ws + off); off += (size_t)NROW * 64 * 2;  // ~10.8 MB

  wprep_kernel<<<dim3((3 * WELEM + 255) / 256), dim3(256), 0, stream>>>(
      Wq, Wk, Wv, WtHi, WtLo);
  proj_kernel<<<dim3(NROW / 16), dim3(256), 0, stream>>>(
      x, WtHi, WtLo, qh, ql, kh, kl, vt);
  attn_kernel<<<dim3(128, BB), dim3(256), 0, stream>>>(
      qh, ql, kh, kl, vt, out);
}

// Round 3
// 200.812 us; speedup vs baseline: 1.0018x; 1.0018x over previous
//
#include <hip/hip_runtime.h>
#include <hip/hip_bf16.h>

// MaskedAttention: out = softmax(tril(q k^T)) v, q/k/v = x @ W{q,k,v}
// B=8 T=2048 D=1024 H=64, fp32 in/out, no 1/sqrt(H) scaling.
//
// Precision plan: q,k projections and QK^T use hi/lo bf16 splitting
// (3-MFMA "bf16x3") so logits are ~fp32-accurate; V/P plain bf16.

typedef __bf16 bf16x8 __attribute__((ext_vector_type(8)));
typedef float f32x4 __attribute__((ext_vector_type(4)));

#define MFMA16(a, b, c) __builtin_amdgcn_mfma_f32_16x16x32_bf16((a), (b), (c), 0, 0, 0)

static constexpr int BB = 8;
static constexpr int TT = 2048;
static constexpr int DD = 1024;
static constexpr int HH = 64;
static constexpr int NROW = BB * TT;       // 16384
static constexpr int WELEM = DD * HH;      // 65536 per matrix

__device__ __forceinline__ float rmax16(float v) {
#pragma unroll
  for (int m = 1; m < 16; m <<= 1) v = fmaxf(v, __shfl_xor(v, m, 64));
  return v;
}
__device__ __forceinline__ float rsum16(float v) {
#pragma unroll
  for (int m = 1; m < 16; m <<= 1) v += __shfl_xor(v, m, 64);
  return v;
}

// ---------------------------------------------------------------- W prep ---
// W [1024][64] fp32 -> Wt hi/lo [3][64][1024] bf16 (transposed, split)
__global__ __launch_bounds__(256) void wprep_kernel(
    const float* __restrict__ Wq, const float* __restrict__ Wk,
    const float* __restrict__ Wv, __bf16* __restrict__ WtHi,
    __bf16* __restrict__ WtLo) {
  int tid = blockIdx.x * 256 + threadIdx.x;
  if (tid >= 3 * WELEM) return;
  int m = tid / WELEM;
  int rem = tid - m * WELEM;
  int d = rem >> 6;
  int h = rem & 63;
  const float* W = (m == 0) ? Wq : ((m == 1) ? Wk : Wv);
  float v = W[d * 64 + h];
  __bf16 hi = (__bf16)v;
  float lo = v - (float)hi;
  size_t o = (size_t)m * WELEM + (size_t)h * 1024 + d;
  WtHi[o] = hi;
  WtLo[o] = (__bf16)lo;
}

// ------------------------------------------------------------ projection ---
// Fused x->bf16(hi/lo) conversion + GEMM. One block (4 waves) per 16-row
// tile; wave w owns column group c=w (16 cols). 4096 waves = 4/SIMD.
// Manual ping-pong double-buffer with two NAMED register sets: R2's version
// let the allocator shrink to 32 VGPRs -> all 7 loads/iter serialized on
// vmcnt(0) (116 us, MfmaUtil 5%). __launch_bounds__(256,4) gives a 128-VGPR
// budget so next-iter loads stay in flight across the MFMA block.
__global__ __launch_bounds__(256, 4) void proj_kernel(
    const float* __restrict__ x, const __bf16* __restrict__ WtHi,
    const __bf16* __restrict__ WtLo, __bf16* __restrict__ qh,
    __bf16* __restrict__ ql, __bf16* __restrict__ kh,
    __bf16* __restrict__ kl, __bf16* __restrict__ vt) {
  const int w = threadIdx.x >> 6, l = threadIdx.x & 63;
  const int lr = l & 15, lg = l >> 4;
  const int r0 = blockIdx.x * 16;
  const int c = w;  // column group (16 cols) owned by this wave

  const float* xp = x + (size_t)(r0 + lr) * DD + lg * 8;
  const size_t wro = (size_t)(c * 16 + lr) * 1024 + lg * 8;
  const __bf16* pqh = WtHi + wro;
  const __bf16* pql = WtLo + wro;
  const __bf16* pkh = WtHi + WELEM + wro;
  const __bf16* pkl = WtLo + WELEM + wro;
  const __bf16* pvh = WtHi + 2 * WELEM + wro;

  f32x4 aq = {0.f, 0.f, 0.f, 0.f};
  f32x4 ak = {0.f, 0.f, 0.f, 0.f};
  f32x4 av = {0.f, 0.f, 0.f, 0.f};

  float4 xa0, xb0; bf16x8 bq0h, bq0l, bk0h, bk0l, bv0h;
  float4 xa1, xb1; bf16x8 bq1h, bq1l, bk1h, bk1l, bv1h;

#define LD(S, d0)                              \
  do {                                         \
    xa##S = *(const float4*)(xp + (d0));       \
    xb##S = *(const float4*)(xp + (d0) + 4);   \
    bq##S##h = *(const bf16x8*)(pqh + (d0));   \
    bq##S##l = *(const bf16x8*)(pql + (d0));   \
    bk##S##h = *(const bf16x8*)(pkh + (d0));   \
    bk##S##l = *(const bf16x8*)(pkl + (d0));   \
    bv##S##h = *(const bf16x8*)(pvh + (d0));   \
  } while (0)

#define CMP(S)                                                        \
  do {                                                                \
    float xs[8] = {xa##S.x, xa##S.y, xa##S.z, xa##S.w,                \
                   xb##S.x, xb##S.y, xb##S.z, xb##S.w};               \
    bf16x8 ah, al;                                                    \
    _Pragma("unroll") for (int j = 0; j < 8; ++j) {                   \
      __bf16 h = (__bf16)xs[j];                                       \
      ah[j] = h;                                                      \
      al[j] = (__bf16)(xs[j] - (float)h);                             \
    }                                                                 \
    aq = MFMA16(ah, bq##S##h, aq);                                    \
    aq = MFMA16(ah, bq##S##l, aq);                                    \
    aq = MFMA16(al, bq##S##h, aq);                                    \
    ak = MFMA16(ah, bk##S##h, ak);                                    \
    ak = MFMA16(ah, bk##S##l, ak);                                    \
    ak = MFMA16(al, bk##S##h, ak);                                    \
    av = MFMA16(ah, bv0h, av);                                        \
  } while (0)

  // NOTE: bv0h in CMP is a bug template risk -- use the S-suffixed one.
#undef CMP
#define CMP(S)                                                        \
  do {                                                                \
    float xs[8] = {xa##S.x, xa##S.y, xa##S.z, xa##S.w,                \
                   xb##S.x, xb##S.y, xb##S.z, xb##S.w};               \
    bf16x8 ah, al;                                                    \
    _Pragma("unroll") for (int j = 0; j < 8; ++j) {                   \
      __bf16 h = (__bf16)xs[j];                                       \
      ah[j] = h;                                                      \
      al[j] = (__bf16)(xs[j] - (float)h);                             \
    }                                                                 \
    aq = MFMA16(ah, bq##S##h, aq);                                    \
    aq = MFMA16(ah, bq##S##l, aq);                                    \
    aq = MFMA16(al, bq##S##h, aq);                                    \
    ak = MFMA16(ah, bk##S##h, ak);                                    \
    ak = MFMA16(ah, bk##S##l, ak);                                    \
    ak = MFMA16(al, bk##S##h, ak);                                    \
    av = MFMA16(ah, bv##S##h, av);                                    \
  } while (0)

  LD(0, 0);
#pragma unroll 1
  for (int d0 = 0; d0 < DD; d0 += 64) {
    LD(1, d0 + 32);   // issue next half-step's loads before computing
    CMP(0);
    if (d0 + 64 < DD) LD(0, d0 + 64);
    CMP(1);
  }
#undef LD
#undef CMP

#pragma unroll
  for (int i = 0; i < 4; ++i) {
    const int row = r0 + lg * 4 + i;  // C-layout: row=(lane>>4)*4+reg
    const int col = c * 16 + lr;      //           col=lane&15
    const size_t oq = (size_t)row * 64 + col;
    float qv = aq[i];
    __bf16 qhi = (__bf16)qv;
    qh[oq] = qhi;
    ql[oq] = (__bf16)(qv - (float)qhi);
    float kv = ak[i];
    __bf16 khi = (__bf16)kv;
    kh[oq] = khi;
    kl[oq] = (__bf16)(kv - (float)khi);
    const int bb = row >> 11, tt = row & 2047;
    vt[((size_t)bb * 64 + col) * 2048 + tt] = (__bf16)av[i];
  }
}

// -------------------------------------------------------------- attention ---
// Split-K flash. One block (4 waves) per 16-row q-tile; waves stride over
// 32-key tiles with private online-softmax state, then LSE-merge via LDS.
// 32-key tiles: QK^T = 3-term split (6 MFMA), fp32 online softmax via 16-lane
// shuffles, P staged bf16 in padded LDS (80B rows), PV = 4 MFMA.
__global__ __launch_bounds__(256) void attn_kernel(
    const __bf16* __restrict__ qh, const __bf16* __restrict__ ql,
    const __bf16* __restrict__ kh, const __bf16* __restrict__ kl,
    const __bf16* __restrict__ vt, float* __restrict__ out) {
  __shared__ __bf16 P[4][16][40];   // 40-col pad: 80B rows -> conflict-free b128
  __shared__ float Sm[4][16];       // per-wave row maxes
  __shared__ float Sl[4][16];       // per-wave row sums
  __shared__ float OB[4][16][68];   // per-wave scaled O (68 pad: <=2-way, free)
  __shared__ float Dinv[16];        // 1/denom per row
  const int w = threadIdx.x >> 6, l = threadIdx.x & 63;
  const int lr = l & 15, lg = l >> 4;
  const int b = blockIdx.y;
  const int qt = 127 - blockIdx.x;  // heavy tiles first (tail shrink)
  const int q0 = qt * 16;
  const float NEG = -__builtin_inff();

  const size_t qb = ((size_t)b * TT + q0 + lr) * 64 + lg * 8;
  const bf16x8 fqh0 = *(const bf16x8*)(qh + qb);
  const bf16x8 fqh1 = *(const bf16x8*)(qh + qb + 32);
  const bf16x8 fql0 = *(const bf16x8*)(ql + qb);
  const bf16x8 fql1 = *(const bf16x8*)(ql + qb + 32);

  f32x4 o0 = {0.f, 0.f, 0.f, 0.f}, o1 = o0, o2 = o0, o3 = o0;
  float m[4] = {NEG, NEG, NEG, NEG};
  float su[4] = {0.f, 0.f, 0.f, 0.f};
  const int nkt = (q0 + 47) >> 5;  // ceil((q0+16)/32)

#pragma unroll 1
  for (int kt = w; kt < nkt; kt += 4) {
    const int j0 = kt * 32;
    const f32x4 z = {0.f, 0.f, 0.f, 0.f};
    f32x4 sa, sb = {NEG, NEG, NEG, NEG};
    {
      const size_t kb = ((size_t)b * TT + j0 + lr) * 64 + lg * 8;
      const bf16x8 fk0 = *(const bf16x8*)(kh + kb);
      const bf16x8 fk1 = *(const bf16x8*)(kh + kb + 32);
      const bf16x8 fl0 = *(const bf16x8*)(kl + kb);
      const bf16x8 fl1 = *(const bf16x8*)(kl + kb + 32);
      f32x4 c0 = MFMA16(fqh1, fk1, MFMA16(fqh0, fk0, z));
      f32x4 c1 = MFMA16(fqh1, fl1, MFMA16(fqh0, fl0, z));
      f32x4 c2 = MFMA16(fql1, fk1, MFMA16(fql0, fk0, z));
      sa = c0 + c1 + c2;
    }
    const bool haveB = (j0 + 16) <= (q0 + 15);
    if (haveB) {
      const size_t kb = ((size_t)b * TT + j0 + 16 + lr) * 64 + lg * 8;
      const bf16x8 fk0 = *(const bf16x8*)(kh + kb);
      const bf16x8 fk1 = *(const bf16x8*)(kh + kb + 32);
      const bf16x8 fl0 = *(const bf16x8*)(kl + kb);
      const bf16x8 fl1 = *(const bf16x8*)(kl + kb + 32);
      f32x4 c0 = MFMA16(fqh1, fk1, MFMA16(fqh0, fk0, z));
      f32x4 c1 = MFMA16(fqh1, fl1, MFMA16(fqh0, fl0, z));
      f32x4 c2 = MFMA16(fql1, fk1, MFMA16(fql0, fk0, z));
      sb = c0 + c1 + c2;
    }
    // causal mask (row = q0 + lg*4 + i, key = j0 [+16] + lr)
#pragma unroll
    for (int i = 0; i < 4; ++i) {
      const int rowg = q0 + lg * 4 + i;
      if (j0 + lr > rowg) sa[i] = NEG;
      if (j0 + 16 + lr > rowg) sb[i] = NEG;
    }
    // online softmax update + stage P in LDS
#pragma unroll
    for (int i = 0; i < 4; ++i) {
      float t = rmax16(fmaxf(sa[i], sb[i]));
      const float mn = fmaxf(m[i], t);
      const float sc = __expf(m[i] - mn);
      m[i] = mn;
      const float pa = __expf(sa[i] - mn);
      const float pb = __expf(sb[i] - mn);
      su[i] = su[i] * sc + rsum16(pa + pb);
      o0[i] *= sc; o1[i] *= sc; o2[i] *= sc; o3[i] *= sc;
      P[w][lg * 4 + i][lr] = (__bf16)pa;
      P[w][lg * 4 + i][16 + lr] = (__bf16)pb;
    }
    // PV: A-frag of P (same-wave LDS ops are in-order; compiler adds waits)
    const bf16x8 pf = *(const bf16x8*)(&P[w][lr][lg * 8]);
    const size_t vb = ((size_t)b * 64 + lr) * 2048 + j0 + lg * 8;
    o0 = MFMA16(pf, *(const bf16x8*)(vt + vb), o0);
    o1 = MFMA16(pf, *(const bf16x8*)(vt + vb + (size_t)16 * 2048), o1);
    o2 = MFMA16(pf, *(const bf16x8*)(vt + vb + (size_t)32 * 2048), o2);
    o3 = MFMA16(pf, *(const bf16x8*)(vt + vb + (size_t)48 * 2048), o3);
  }

  // ------- LSE merge of the 4 per-wave partials -------
  if (lr == 0) {
#pragma unroll
    for (int i = 0; i < 4; ++i) {
      Sm[w][lg * 4 + i] = m[i];
      Sl[w][lg * 4 + i] = su[i];
    }
  }
  __syncthreads();
#pragma unroll
  for (int i = 0; i < 4; ++i) {
    const int row = lg * 4 + i;
    float M = fmaxf(fmaxf(Sm[0][row], Sm[1][row]),
                    fmaxf(Sm[2][row], Sm[3][row]));
    const float sc = __expf(m[i] - M);  // 0 if this wave was idle (m=-inf)
    OB[w][row][lr] = o0[i] * sc;
    OB[w][row][16 + lr] = o1[i] * sc;
    OB[w][row][32 + lr] = o2[i] * sc;
    OB[w][row][48 + lr] = o3[i] * sc;
    if (w == 0 && lr == 0) {
      float denom = 0.f;
#pragma unroll
      for (int w2 = 0; w2 < 4; ++w2)
        denom += Sl[w2][row] * __expf(Sm[w2][row] - M);
      Dinv[row] = 1.0f / denom;
    }
  }
  __syncthreads();
  const int t = threadIdx.x;
#pragma unroll
  for (int k2 = 0; k2 < 4; ++k2) {
    const int e = t + 256 * k2;
    const int row = e >> 6, col = e & 63;
    const float s = OB[0][row][col] + OB[1][row][col] + OB[2][row][col] +
                    OB[3][row][col];
    out[((size_t)b * TT + q0 + row) * 64 + col] = s * Dinv[row];
  }
}

// ------------------------------------------------------------------ launch ---
extern "C" void kernel_launch(void* const* d_in, const int* in_sizes, int n_in,
                              void* d_out, int out_size, void* d_ws,
                              size_t ws_size, hipStream_t stream) {
  const float* x = (const float*)d_in[0];
  const float* Wq = (const float*)d_in[1];
  const float* Wk = (const float*)d_in[2];
  const float* Wv = (const float*)d_in[3];
  float* out = (float*)d_out;
  char* ws = (char*)d_ws;

  size_t off = 0;
  __bf16* WtHi = (__bf16*)(ws + off); off += (size_t)3 * WELEM * 2;
  __bf16* WtLo = (__bf16*)(ws + off); off += (size_t)3 * WELEM * 2;
  __bf16* qh = (__bf16*)(ws + off); off += (size_t)NROW * 64 * 2;
  __bf16* ql = (__bf16*)(ws + off); off += (size_t)NROW * 64 * 2;
  __bf16* kh = (__bf16*)(ws + off); off += (size_t)NROW * 64 * 2;
  __bf16* kl = (__bf16*)(ws + off); off += (size_t)NROW * 64 * 2;
  __bf16* vt = (__bf16*)(ws + off); off += (size_t)NROW * 64 * 2;  // ~10.8 MB

  wprep_kernel<<<dim3((3 * WELEM + 255) / 256), dim3(256), 0, stream>>>(
      Wq, Wk, Wv, WtHi, WtLo);
  proj_kernel<<<dim3(NROW / 16), dim3(256), 0, stream>>>(
      x, WtHi, WtLo, qh, ql, kh, kl, vt);
  attn_kernel<<<dim3(128, BB), dim3(256), 0, stream>>>(
      qh, ql, kh, kl, vt, out);
}

// Round 4
// 173.423 us; speedup vs baseline: 1.1600x; 1.1579x over previous
//
#include <hip/hip_runtime.h>
#include <hip/hip_bf16.h>

// MaskedAttention: out = softmax(tril(q k^T)) v, q/k/v = x @ W{q,k,v}
// B=8 T=2048 D=1024 H=64, fp32 in/out, no 1/sqrt(H) scaling.
//
// Precision plan: q,k projections and QK^T use hi/lo bf16 splitting
// (3-MFMA "bf16x3") so logits are ~fp32-accurate; V/P plain bf16.

typedef __bf16 bf16x8 __attribute__((ext_vector_type(8)));
typedef float f32x4 __attribute__((ext_vector_type(4)));

#define MFMA16(a, b, c) __builtin_amdgcn_mfma_f32_16x16x32_bf16((a), (b), (c), 0, 0, 0)
#define SB0() __builtin_amdgcn_sched_barrier(0)

static constexpr int BB = 8;
static constexpr int TT = 2048;
static constexpr int DD = 1024;
static constexpr int HH = 64;
static constexpr int NROW = BB * TT;       // 16384

__device__ __forceinline__ float rmax16(float v) {
#pragma unroll
  for (int m = 1; m < 16; m <<= 1) v = fmaxf(v, __shfl_xor(v, m, 64));
  return v;
}
__device__ __forceinline__ float rsum16(float v) {
#pragma unroll
  for (int m = 1; m < 16; m <<= 1) v += __shfl_xor(v, m, 64);
  return v;
}

// ---------------------------------------------------------------- W prep ---
// W [1024][64] fp32 -> WC interleaved slab:
// WC[(col*128 + k8)*40 + m*8 + j] = frag m of W[k8*8+j][col],
// m: 0=q_hi 1=q_lo 2=k_hi 3=k_lo 4=v_hi. 655 KB total; lets proj read all
// five 16B fragments at immediate offsets 0/16/32/48/64 off ONE address.
__global__ __launch_bounds__(256) void wprep_kernel(
    const float* __restrict__ Wq, const float* __restrict__ Wk,
    const float* __restrict__ Wv, __bf16* __restrict__ WC) {
  int tid = blockIdx.x * 256 + threadIdx.x;
  if (tid >= 64 * 128) return;
  int col = tid >> 7;
  int k8 = tid & 127;
  bf16x8 q_h, q_l, k_h, k_l, v_h;
#pragma unroll
  for (int j = 0; j < 8; ++j) {
    const int k = k8 * 8 + j;
    float qv = Wq[k * 64 + col];
    float kv = Wk[k * 64 + col];
    float vv = Wv[k * 64 + col];
    __bf16 qhi = (__bf16)qv;
    __bf16 khi = (__bf16)kv;
    q_h[j] = qhi;
    q_l[j] = (__bf16)(qv - (float)qhi);
    k_h[j] = khi;
    k_l[j] = (__bf16)(kv - (float)khi);
    v_h[j] = (__bf16)vv;
  }
  __bf16* base = WC + (size_t)tid * 40;
  *(bf16x8*)(base) = q_h;
  *(bf16x8*)(base + 8) = q_l;
  *(bf16x8*)(base + 16) = k_h;
  *(bf16x8*)(base + 24) = k_l;
  *(bf16x8*)(base + 32) = v_h;
}

// ------------------------------------------------------------ projection ---
// One block (4 waves) per 16-row tile; wave w owns column group c=w (16
// cols). 4096 waves = 4/SIMD, all co-resident. Hand-pipelined: x fragments
// depth-4 (HBM ~900cy), W fragments depth-2 (L2 ~200cy), sched_barrier(0)
// after each {CMP, reload} group so the scheduler cannot sink loads (R3
// post-mortem: without pinning, hipcc serializes every load at ~400cy).
__global__ __launch_bounds__(256, 4) void proj_kernel(
    const float* __restrict__ x, const __bf16* __restrict__ WC,
    __bf16* __restrict__ qh, __bf16* __restrict__ ql,
    __bf16* __restrict__ kh, __bf16* __restrict__ kl,
    __bf16* __restrict__ vt) {
  const int w = threadIdx.x >> 6, l = threadIdx.x & 63;
  const int lr = l & 15, lg = l >> 4;
  const int r0 = blockIdx.x * 16;
  const int c = w;  // column group (16 cols) owned by this wave

  const float* xp = x + (size_t)(r0 + lr) * DD + lg * 8;
  // per-lane W slab pointer: cell (col=c*16+lr, k8=lg), 80B cells
  const __bf16* wcp = WC + ((size_t)(c * 16 + lr) * 128 + lg) * 40;

  f32x4 aq = {0.f, 0.f, 0.f, 0.f};
  f32x4 ak = {0.f, 0.f, 0.f, 0.f};
  f32x4 av = {0.f, 0.f, 0.f, 0.f};

  float4 xa0, xb0, xa1, xb1, xa2, xb2, xa3, xb3;
  bf16x8 uq0h, uq0l, uk0h, uk0l, uv0;
  bf16x8 uq1h, uq1l, uk1h, uk1l, uv1;

#define LDX(S, off)                               \
  do {                                            \
    xa##S = *(const float4*)(xp + (off));         \
    xb##S = *(const float4*)(xp + (off) + 4);     \
  } while (0)

#define LDU(T, off)                               \
  do {                                            \
    const __bf16* p = wcp + (size_t)(off) * 5;    \
    uq##T##h = *(const bf16x8*)(p);               \
    uq##T##l = *(const bf16x8*)(p + 8);           \
    uk##T##h = *(const bf16x8*)(p + 16);          \
    uk##T##l = *(const bf16x8*)(p + 24);          \
    uv##T = *(const bf16x8*)(p + 32);             \
  } while (0)

#define CMP(S, T)                                                     \
  do {                                                                \
    float xs[8] = {xa##S.x, xa##S.y, xa##S.z, xa##S.w,                \
                   xb##S.x, xb##S.y, xb##S.z, xb##S.w};               \
    bf16x8 ah, al;                                                    \
    _Pragma("unroll") for (int j = 0; j < 8; ++j) {                   \
      __bf16 h = (__bf16)xs[j];                                       \
      ah[j] = h;                                                      \
      al[j] = (__bf16)(xs[j] - (float)h);                             \
    }                                                                 \
    aq = MFMA16(ah, uq##T##h, aq);                                    \
    aq = MFMA16(ah, uq##T##l, aq);                                    \
    aq = MFMA16(al, uq##T##h, aq);                                    \
    ak = MFMA16(ah, uk##T##h, ak);                                    \
    ak = MFMA16(ah, uk##T##l, ak);                                    \
    ak = MFMA16(al, uk##T##h, ak);                                    \
    av = MFMA16(ah, uv##T, av);                                       \
  } while (0)

  // prologue: x steps 0,32,64,96 in flight; W steps 0,32 in flight
  LDX(0, 0); LDX(1, 32); LDX(2, 64); LDX(3, 96);
  LDU(0, 0); LDU(1, 32);

#pragma unroll 1
  for (int d0 = 0; d0 < DD - 128; d0 += 128) {
    CMP(0, 0); LDU(0, d0 + 64);  LDX(0, d0 + 128); SB0();
    CMP(1, 1); LDU(1, d0 + 96);  LDX(1, d0 + 160); SB0();
    CMP(2, 0); LDU(0, d0 + 128); LDX(2, d0 + 192); SB0();
    CMP(3, 1); LDU(1, d0 + 160); LDX(3, d0 + 224); SB0();
  }
  // epilogue: steps 896,928,960,992 (x preloaded; W needs 960,992)
  CMP(0, 0); LDU(0, DD - 64); SB0();
  CMP(1, 1); LDU(1, DD - 32); SB0();
  CMP(2, 0);
  CMP(3, 1);

#undef LDX
#undef LDU
#undef CMP

#pragma unroll
  for (int i = 0; i < 4; ++i) {
    const int row = r0 + lg * 4 + i;  // C-layout: row=(lane>>4)*4+reg
    const int col = c * 16 + lr;      //           col=lane&15
    const size_t oq = (size_t)row * 64 + col;
    float qv = aq[i];
    __bf16 qhi = (__bf16)qv;
    qh[oq] = qhi;
    ql[oq] = (__bf16)(qv - (float)qhi);
    float kv = ak[i];
    __bf16 khi = (__bf16)kv;
    kh[oq] = khi;
    kl[oq] = (__bf16)(kv - (float)khi);
    const int bb = row >> 11, tt = row & 2047;
    vt[((size_t)bb * 64 + col) * 2048 + tt] = (__bf16)av[i];
  }
}

// -------------------------------------------------------------- attention ---
// Split-K flash. One block (4 waves) per 16-row q-tile; waves stride over
// 32-key tiles with private online-softmax state, then LSE-merge via LDS.
// XCD swizzle: flat grid, b = blockIdx.x & 7 -> all blocks of batch b land
// on one XCD (round-robin dispatch), K/V working set 768KB = L2-resident.
// All 12 loads issued at loop top + sched_barrier(0): V stays in flight
// under ~300cy of softmax (counted vmcnt), K-B under QK-A.
__global__ __launch_bounds__(256, 4) void attn_kernel(
    const __bf16* __restrict__ qh, const __bf16* __restrict__ ql,
    const __bf16* __restrict__ kh, const __bf16* __restrict__ kl,
    const __bf16* __restrict__ vt, float* __restrict__ out) {
  __shared__ __bf16 P[4][16][40];   // 40-col pad: 80B rows -> conflict-free b128
  __shared__ float Sm[4][16];       // per-wave row maxes
  __shared__ float Sl[4][16];       // per-wave row sums
  __shared__ float OB[4][16][68];   // per-wave scaled O (68 pad: <=2-way, free)
  __shared__ float Dinv[16];        // 1/denom per row
  const int w = threadIdx.x >> 6, l = threadIdx.x & 63;
  const int lr = l & 15, lg = l >> 4;
  const int b = blockIdx.x & 7;            // XCD affinity: batch -> XCD
  const int qt = 127 - (blockIdx.x >> 3);  // heavy tiles first
  const int q0 = qt * 16;
  const float NEG = -__builtin_inff();

  const size_t qb = ((size_t)b * TT + q0 + lr) * 64 + lg * 8;
  const bf16x8 fqh0 = *(const bf16x8*)(qh + qb);
  const bf16x8 fqh1 = *(const bf16x8*)(qh + qb + 32);
  const bf16x8 fql0 = *(const bf16x8*)(ql + qb);
  const bf16x8 fql1 = *(const bf16x8*)(ql + qb + 32);

  f32x4 o0 = {0.f, 0.f, 0.f, 0.f}, o1 = o0, o2 = o0, o3 = o0;
  float m[4] = {NEG, NEG, NEG, NEG};
  float su[4] = {0.f, 0.f, 0.f, 0.f};
  const int nkt = (q0 + 47) >> 5;  // ceil((q0+16)/32)

#pragma unroll 1
  for (int kt = w; kt < nkt; kt += 4) {
    const int j0 = kt * 32;
    const f32x4 z = {0.f, 0.f, 0.f, 0.f};
    // ---- all loads up front (KB unconditional: in-bounds, masked later) ----
    const size_t kbA = ((size_t)b * TT + j0 + lr) * 64 + lg * 8;
    const size_t kbB = kbA + (size_t)16 * 64;
    const size_t vb = ((size_t)b * 64 + lr) * 2048 + j0 + lg * 8;
    const bf16x8 fk0 = *(const bf16x8*)(kh + kbA);
    const bf16x8 fk1 = *(const bf16x8*)(kh + kbA + 32);
    const bf16x8 fl0 = *(const bf16x8*)(kl + kbA);
    const bf16x8 fl1 = *(const bf16x8*)(kl + kbA + 32);
    const bf16x8 gk0 = *(const bf16x8*)(kh + kbB);
    const bf16x8 gk1 = *(const bf16x8*)(kh + kbB + 32);
    const bf16x8 gl0 = *(const bf16x8*)(kl + kbB);
    const bf16x8 gl1 = *(const bf16x8*)(kl + kbB + 32);
    const bf16x8 v0 = *(const bf16x8*)(vt + vb);
    const bf16x8 v1 = *(const bf16x8*)(vt + vb + (size_t)16 * 2048);
    const bf16x8 v2 = *(const bf16x8*)(vt + vb + (size_t)32 * 2048);
    const bf16x8 v3 = *(const bf16x8*)(vt + vb + (size_t)48 * 2048);
    SB0();  // loads may not sink past this point

    f32x4 sa, sb = {NEG, NEG, NEG, NEG};
    {
      f32x4 c0 = MFMA16(fqh1, fk1, MFMA16(fqh0, fk0, z));
      f32x4 c1 = MFMA16(fqh1, fl1, MFMA16(fqh0, fl0, z));
      f32x4 c2 = MFMA16(fql1, fk1, MFMA16(fql0, fk0, z));
      sa = c0 + c1 + c2;
    }
    const bool haveB = (j0 + 16) <= (q0 + 15);
    if (haveB) {
      f32x4 c0 = MFMA16(fqh1, gk1, MFMA16(fqh0, gk0, z));
      f32x4 c1 = MFMA16(fqh1, gl1, MFMA16(fqh0, gl0, z));
      f32x4 c2 = MFMA16(fql1, gk1, MFMA16(fql0, gk0, z));
      sb = c0 + c1 + c2;
    }
    // causal mask (row = q0 + lg*4 + i, key = j0 [+16] + lr)
#pragma unroll
    for (int i = 0; i < 4; ++i) {
      const int rowg = q0 + lg * 4 + i;
      if (j0 + lr > rowg) sa[i] = NEG;
      if (j0 + 16 + lr > rowg) sb[i] = NEG;
    }
    // online softmax update + stage P in LDS
#pragma unroll
    for (int i = 0; i < 4; ++i) {
      float t = rmax16(fmaxf(sa[i], sb[i]));
      const float mn = fmaxf(m[i], t);
      const float sc = __expf(m[i] - mn);
      m[i] = mn;
      const float pa = __expf(sa[i] - mn);
      const float pb = __expf(sb[i] - mn);
      su[i] = su[i] * sc + rsum16(pa + pb);
      o0[i] *= sc; o1[i] *= sc; o2[i] *= sc; o3[i] *= sc;
      P[w][lg * 4 + i][lr] = (__bf16)pa;
      P[w][lg * 4 + i][16 + lr] = (__bf16)pb;
    }
    // PV: A-frag of P (same-wave LDS ops are in-order; compiler adds waits)
    const bf16x8 pf = *(const bf16x8*)(&P[w][lr][lg * 8]);
    o0 = MFMA16(pf, v0, o0);
    o1 = MFMA16(pf, v1, o1);
    o2 = MFMA16(pf, v2, o2);
    o3 = MFMA16(pf, v3, o3);
  }

  // ------- LSE merge of the 4 per-wave partials -------
  if (lr == 0) {
#pragma unroll
    for (int i = 0; i < 4; ++i) {
      Sm[w][lg * 4 + i] = m[i];
      Sl[w][lg * 4 + i] = su[i];
    }
  }
  __syncthreads();
#pragma unroll
  for (int i = 0; i < 4; ++i) {
    const int row = lg * 4 + i;
    float M = fmaxf(fmaxf(Sm[0][row], Sm[1][row]),
                    fmaxf(Sm[2][row], Sm[3][row]));
    const float sc = __expf(m[i] - M);  // 0 if this wave was idle (m=-inf)
    OB[w][row][lr] = o0[i] * sc;
    OB[w][row][16 + lr] = o1[i] * sc;
    OB[w][row][32 + lr] = o2[i] * sc;
    OB[w][row][48 + lr] = o3[i] * sc;
    if (w == 0 && lr == 0) {
      float denom = 0.f;
#pragma unroll
      for (int w2 = 0; w2 < 4; ++w2)
        denom += Sl[w2][row] * __expf(Sm[w2][row] - M);
      Dinv[row] = 1.0f / denom;
    }
  }
  __syncthreads();
  const int t = threadIdx.x;
#pragma unroll
  for (int k2 = 0; k2 < 4; ++k2) {
    const int e = t + 256 * k2;
    const int row = e >> 6, col = e & 63;
    const float s = OB[0][row][col] + OB[1][row][col] + OB[2][row][col] +
                    OB[3][row][col];
    out[((size_t)b * TT + q0 + row) * 64 + col] = s * Dinv[row];
  }
}

// ------------------------------------------------------------------ launch ---
extern "C" void kernel_launch(void* const* d_in, const int* in_sizes, int n_in,
                              void* d_out, int out_size, void* d_ws,
                              size_t ws_size, hipStream_t stream) {
  const float* x = (const float*)d_in[0];
  const float* Wq = (const float*)d_in[1];
  const float* Wk = (const float*)d_in[2];
  const float* Wv = (const float*)d_in[3];
  float* out = (float*)d_out;
  char* ws = (char*)d_ws;

  size_t off = 0;
  __bf16* WC = (__bf16*)(ws + off); off += (size_t)64 * 128 * 40 * 2;  // 655KB
  __bf16* qh = (__bf16*)(ws + off); off += (size_t)NROW * 64 * 2;
  __bf16* ql = (__bf16*)(ws + off); off += (size_t)NROW * 64 * 2;
  __bf16* kh = (__bf16*)(ws + off); off += (size_t)NROW * 64 * 2;
  __bf16* kl = (__bf16*)(ws + off); off += (size_t)NROW * 64 * 2;
  __bf16* vt = (__bf16*)(ws + off); off += (size_t)NROW * 64 * 2;  // ~11.1 MB

  wprep_kernel<<<dim3(32), dim3(256), 0, stream>>>(Wq, Wk, Wv, WC);
  proj_kernel<<<dim3(NROW / 16), dim3(256), 0, stream>>>(
      x, WC, qh, ql, kh, kl, vt);
  attn_kernel<<<dim3(1024), dim3(256), 0, stream>>>(
      qh, ql, kh, kl, vt, out);
}

// Round 5
// 107.765 us; speedup vs baseline: 1.8668x; 1.6093x over previous
//
#include <hip/hip_runtime.h>
#include <hip/hip_bf16.h>

// MaskedAttention: out = softmax(tril(q k^T)) v, q/k/v = x @ W{q,k,v}
// B=8 T=2048 D=1024 H=64, fp32 in/out, no 1/sqrt(H) scaling.
//
// Precision plan: q,k projections and QK^T use hi/lo bf16 splitting
// (3-MFMA "bf16x3") so logits are ~fp32-accurate; V/P plain bf16.

typedef __bf16 bf16x8 __attribute__((ext_vector_type(8)));
typedef float f32x4 __attribute__((ext_vector_type(4)));

#define MFMA16(a, b, c) __builtin_amdgcn_mfma_f32_16x16x32_bf16((a), (b), (c), 0, 0, 0)
#define SB0() __builtin_amdgcn_sched_barrier(0)

static constexpr int BB = 8;
static constexpr int TT = 2048;
static constexpr int DD = 1024;
static constexpr int HH = 64;
static constexpr int NROW = BB * TT;       // 16384
// WC slab: [4 colgroups][2 K-halves][320 rows = k8l*5+frag][16 cols][8 bf16]
// frag: 0=q_hi 1=q_lo 2=k_hi 3=k_lo 4=v_hi. 80KB per (cg,half) slice.
static constexpr int WSLICE = 320 * 128;   // bf16 elems per (cg,half) = 80KB

__device__ __forceinline__ float rmax16(float v) {
#pragma unroll
  for (int m = 1; m < 16; m <<= 1) v = fmaxf(v, __shfl_xor(v, m, 64));
  return v;
}
__device__ __forceinline__ float rsum16(float v) {
#pragma unroll
  for (int m = 1; m < 16; m <<= 1) v += __shfl_xor(v, m, 64);
  return v;
}

// ---------------------------------------------------------------- W prep ---
// W [1024][64] fp32 -> WC slab (see above). Linear in (row,col) so proj can
// stage it to LDS with pure linear global_load_lds DMA.
__global__ __launch_bounds__(256) void wprep_kernel(
    const float* __restrict__ Wq, const float* __restrict__ Wk,
    const float* __restrict__ Wv, __bf16* __restrict__ WC) {
  int tid = blockIdx.x * 256 + threadIdx.x;
  if (tid >= 64 * 128) return;
  int col = tid >> 7;
  int k8 = tid & 127;
  const int g = col >> 4, c = col & 15;
  const int h2 = k8 >> 6, k8l = k8 & 63;
  bf16x8 q_h, q_l, k_h, k_l, v_h;
#pragma unroll
  for (int j = 0; j < 8; ++j) {
    const int k = k8 * 8 + j;
    float qv = Wq[k * 64 + col];
    float kv = Wk[k * 64 + col];
    float vv = Wv[k * 64 + col];
    __bf16 qhi = (__bf16)qv;
    __bf16 khi = (__bf16)kv;
    q_h[j] = qhi;
    q_l[j] = (__bf16)(qv - (float)qhi);
    k_h[j] = khi;
    k_l[j] = (__bf16)(kv - (float)khi);
    v_h[j] = (__bf16)vv;
  }
  __bf16* base = WC + (size_t)(g * 2 + h2) * WSLICE + (size_t)(k8l * 5) * 128 + c * 8;
  *(bf16x8*)(base) = q_h;            // row k8l*5+0
  *(bf16x8*)(base + 128) = q_l;      // row k8l*5+1
  *(bf16x8*)(base + 256) = k_h;      // row k8l*5+2
  *(bf16x8*)(base + 384) = k_l;      // row k8l*5+3
  *(bf16x8*)(base + 512) = v_h;      // row k8l*5+4
}

// ------------------------------------------------------------ projection ---
// Block = 512 threads (8 waves): 128 rows x ONE 16-col group, K in 2 halves.
// Per half: stage the 80KB W slice into LDS (10x global_load_lds dwordx4
// per thread, one barrier) -- all 8 waves share it (W L2 traffic /8, and
// the DMA engine eats the global latency that killed R2-R4's reg staging).
// Main loop: per 32-K step, 2 x-loads (depth-4 rotation + SB0), 5 conflict-
// free ds_read_b128 (frag read = 4 dense 256B rows), 7 MFMA.
// Grid 512: rg=bid&127, cg=bid>>7 -> same-x blocks share an XCD L2.
__global__ __launch_bounds__(512, 4) void proj_kernel(
    const float* __restrict__ x, const __bf16* __restrict__ WC,
    __bf16* __restrict__ qh, __bf16* __restrict__ ql,
    __bf16* __restrict__ kh, __bf16* __restrict__ kl,
    __bf16* __restrict__ vt) {
  __shared__ __bf16 Wlds[WSLICE];  // 80 KB
  const int tid = threadIdx.x;
  const int w = tid >> 6, l = tid & 63;
  const int lr = l & 15, lg = l >> 4;
  const int rg = blockIdx.x & 127, cg = blockIdx.x >> 7;
  const int r0 = rg * 128 + w * 16;

  const float* xp = x + (size_t)(r0 + lr) * DD + lg * 8;
  // per-frag LDS base (bf16 elems): row (5*lg+m), chunk lr
  const int wb0 = (5 * lg + 0) * 128 + lr * 8;

  f32x4 aq = {0.f, 0.f, 0.f, 0.f};
  f32x4 ak = {0.f, 0.f, 0.f, 0.f};
  f32x4 av = {0.f, 0.f, 0.f, 0.f};
  float4 xa[4], xb[4];

#define LDX(J, OFF)                               \
  do {                                            \
    xa[J] = *(const float4*)(xp + (OFF));         \
    xb[J] = *(const float4*)(xp + (OFF) + 4);     \
  } while (0)

#define CMPW(J, S)                                                    \
  do {                                                                \
    const __bf16* fp = &Wlds[(S) * 2560 + wb0];                       \
    bf16x8 f0 = *(const bf16x8*)(fp);                                 \
    bf16x8 f1 = *(const bf16x8*)(fp + 128);                           \
    bf16x8 f2 = *(const bf16x8*)(fp + 256);                           \
    bf16x8 f3 = *(const bf16x8*)(fp + 384);                           \
    bf16x8 f4 = *(const bf16x8*)(fp + 512);                           \
    float xs[8] = {xa[J].x, xa[J].y, xa[J].z, xa[J].w,                \
                   xb[J].x, xb[J].y, xb[J].z, xb[J].w};               \
    bf16x8 ah, al;                                                    \
    _Pragma("unroll") for (int j = 0; j < 8; ++j) {                   \
      __bf16 hv = (__bf16)xs[j];                                      \
      ah[j] = hv;                                                     \
      al[j] = (__bf16)(xs[j] - (float)hv);                            \
    }                                                                 \
    aq = MFMA16(ah, f0, aq);                                          \
    aq = MFMA16(ah, f1, aq);                                          \
    aq = MFMA16(al, f0, aq);                                          \
    ak = MFMA16(ah, f2, ak);                                          \
    ak = MFMA16(ah, f3, ak);                                          \
    ak = MFMA16(al, f2, ak);                                          \
    av = MFMA16(ah, f4, av);                                          \
  } while (0)

#pragma unroll 1
  for (int h = 0; h < 2; ++h) {
    if (h) __syncthreads();  // all waves done reading half-0 W
    {
      const __bf16* wsrc = WC + (size_t)(cg * 2 + h) * WSLICE;
      const __bf16* gp = wsrc + (size_t)tid * 8;  // per-lane 16B cell
#pragma unroll
      for (int i2 = 0; i2 < 10; ++i2) {
        __builtin_amdgcn_global_load_lds(
            (const __attribute__((address_space(1))) unsigned int*)(gp + i2 * 4096),
            (__attribute__((address_space(3))) unsigned int*)
                ((char*)Wlds + w * 1024 + i2 * 8192),
            16, 0, 0);
      }
    }
    __syncthreads();  // compiler drains vmcnt before barrier: DMA complete

    const int xoff = h * 512;
    LDX(0, xoff); LDX(1, xoff + 32); LDX(2, xoff + 64); LDX(3, xoff + 96);
    SB0();
#pragma unroll
    for (int s = 0; s < 16; ++s) {
      CMPW(s & 3, s);
      if (s < 12) LDX(s & 3, xoff + (s + 4) * 32);
      SB0();
    }
  }
#undef LDX
#undef CMPW

#pragma unroll
  for (int i = 0; i < 4; ++i) {
    const int row = r0 + lg * 4 + i;  // C-layout: row=(lane>>4)*4+reg
    const int col = cg * 16 + lr;     //           col=lane&15
    const size_t oq = (size_t)row * 64 + col;
    float qv = aq[i];
    __bf16 qhi = (__bf16)qv;
    qh[oq] = qhi;
    ql[oq] = (__bf16)(qv - (float)qhi);
    float kv = ak[i];
    __bf16 khi = (__bf16)kv;
    kh[oq] = khi;
    kl[oq] = (__bf16)(kv - (float)khi);
    const int bb = row >> 11, tt = row & 2047;
    vt[((size_t)bb * 64 + col) * 2048 + tt] = (__bf16)av[i];
  }
}

// -------------------------------------------------------------- attention ---
// Split-K flash. One block (4 waves) per 16-row q-tile; waves stride over
// 32-key tiles with private online-softmax state, then LSE-merge via LDS.
// XCD swizzle: flat grid, b = blockIdx.x & 7 -> all blocks of batch b land
// on one XCD (round-robin dispatch), K/V working set 768KB = L2-resident.
// All 12 loads issued at loop top + sched_barrier(0): V stays in flight
// under ~300cy of softmax (counted vmcnt), K-B under QK-A.
__global__ __launch_bounds__(256, 4) void attn_kernel(
    const __bf16* __restrict__ qh, const __bf16* __restrict__ ql,
    const __bf16* __restrict__ kh, const __bf16* __restrict__ kl,
    const __bf16* __restrict__ vt, float* __restrict__ out) {
  __shared__ __bf16 P[4][16][40];   // 40-col pad: 80B rows -> conflict-free b128
  __shared__ float Sm[4][16];       // per-wave row maxes
  __shared__ float Sl[4][16];       // per-wave row sums
  __shared__ float OB[4][16][68];   // per-wave scaled O (68 pad: <=2-way, free)
  __shared__ float Dinv[16];        // 1/denom per row
  const int w = threadIdx.x >> 6, l = threadIdx.x & 63;
  const int lr = l & 15, lg = l >> 4;
  const int b = blockIdx.x & 7;            // XCD affinity: batch -> XCD
  const int qt = 127 - (blockIdx.x >> 3);  // heavy tiles first
  const int q0 = qt * 16;
  const float NEG = -__builtin_inff();

  const size_t qb = ((size_t)b * TT + q0 + lr) * 64 + lg * 8;
  const bf16x8 fqh0 = *(const bf16x8*)(qh + qb);
  const bf16x8 fqh1 = *(const bf16x8*)(qh + qb + 32);
  const bf16x8 fql0 = *(const bf16x8*)(ql + qb);
  const bf16x8 fql1 = *(const bf16x8*)(ql + qb + 32);

  f32x4 o0 = {0.f, 0.f, 0.f, 0.f}, o1 = o0, o2 = o0, o3 = o0;
  float m[4] = {NEG, NEG, NEG, NEG};
  float su[4] = {0.f, 0.f, 0.f, 0.f};
  const int nkt = (q0 + 47) >> 5;  // ceil((q0+16)/32)

#pragma unroll 1
  for (int kt = w; kt < nkt; kt += 4) {
    const int j0 = kt * 32;
    const f32x4 z = {0.f, 0.f, 0.f, 0.f};
    // ---- all loads up front (KB unconditional: in-bounds, masked later) ----
    const size_t kbA = ((size_t)b * TT + j0 + lr) * 64 + lg * 8;
    const size_t kbB = kbA + (size_t)16 * 64;
    const size_t vb = ((size_t)b * 64 + lr) * 2048 + j0 + lg * 8;
    const bf16x8 fk0 = *(const bf16x8*)(kh + kbA);
    const bf16x8 fk1 = *(const bf16x8*)(kh + kbA + 32);
    const bf16x8 fl0 = *(const bf16x8*)(kl + kbA);
    const bf16x8 fl1 = *(const bf16x8*)(kl + kbA + 32);
    const bf16x8 gk0 = *(const bf16x8*)(kh + kbB);
    const bf16x8 gk1 = *(const bf16x8*)(kh + kbB + 32);
    const bf16x8 gl0 = *(const bf16x8*)(kl + kbB);
    const bf16x8 gl1 = *(const bf16x8*)(kl + kbB + 32);
    const bf16x8 v0 = *(const bf16x8*)(vt + vb);
    const bf16x8 v1 = *(const bf16x8*)(vt + vb + (size_t)16 * 2048);
    const bf16x8 v2 = *(const bf16x8*)(vt + vb + (size_t)32 * 2048);
    const bf16x8 v3 = *(const bf16x8*)(vt + vb + (size_t)48 * 2048);
    SB0();  // loads may not sink past this point

    f32x4 sa, sb = {NEG, NEG, NEG, NEG};
    {
      f32x4 c0 = MFMA16(fqh1, fk1, MFMA16(fqh0, fk0, z));
      f32x4 c1 = MFMA16(fqh1, fl1, MFMA16(fqh0, fl0, z));
      f32x4 c2 = MFMA16(fql1, fk1, MFMA16(fql0, fk0, z));
      sa = c0 + c1 + c2;
    }
    const bool haveB = (j0 + 16) <= (q0 + 15);
    if (haveB) {
      f32x4 c0 = MFMA16(fqh1, gk1, MFMA16(fqh0, gk0, z));
      f32x4 c1 = MFMA16(fqh1, gl1, MFMA16(fqh0, gl0, z));
      f32x4 c2 = MFMA16(fql1, gk1, MFMA16(fql0, gk0, z));
      sb = c0 + c1 + c2;
    }
    // causal mask (row = q0 + lg*4 + i, key = j0 [+16] + lr)
#pragma unroll
    for (int i = 0; i < 4; ++i) {
      const int rowg = q0 + lg * 4 + i;
      if (j0 + lr > rowg) sa[i] = NEG;
      if (j0 + 16 + lr > rowg) sb[i] = NEG;
    }
    // online softmax update + stage P in LDS
#pragma unroll
    for (int i = 0; i < 4; ++i) {
      float t = rmax16(fmaxf(sa[i], sb[i]));
      const float mn = fmaxf(m[i], t);
      const float sc = __expf(m[i] - mn);
      m[i] = mn;
      const float pa = __expf(sa[i] - mn);
      const float pb = __expf(sb[i] - mn);
      su[i] = su[i] * sc + rsum16(pa + pb);
      o0[i] *= sc; o1[i] *= sc; o2[i] *= sc; o3[i] *= sc;
      P[w][lg * 4 + i][lr] = (__bf16)pa;
      P[w][lg * 4 + i][16 + lr] = (__bf16)pb;
    }
    // PV: A-frag of P (same-wave LDS ops are in-order; compiler adds waits)
    const bf16x8 pf = *(const bf16x8*)(&P[w][lr][lg * 8]);
    o0 = MFMA16(pf, v0, o0);
    o1 = MFMA16(pf, v1, o1);
    o2 = MFMA16(pf, v2, o2);
    o3 = MFMA16(pf, v3, o3);
  }

  // ------- LSE merge of the 4 per-wave partials -------
  if (lr == 0) {
#pragma unroll
    for (int i = 0; i < 4; ++i) {
      Sm[w][lg * 4 + i] = m[i];
      Sl[w][lg * 4 + i] = su[i];
    }
  }
  __syncthreads();
#pragma unroll
  for (int i = 0; i < 4; ++i) {
    const int row = lg * 4 + i;
    float M = fmaxf(fmaxf(Sm[0][row], Sm[1][row]),
                    fmaxf(Sm[2][row], Sm[3][row]));
    const float sc = __expf(m[i] - M);  // 0 if this wave was idle (m=-inf)
    OB[w][row][lr] = o0[i] * sc;
    OB[w][row][16 + lr] = o1[i] * sc;
    OB[w][row][32 + lr] = o2[i] * sc;
    OB[w][row][48 + lr] = o3[i] * sc;
    if (w == 0 && lr == 0) {
      float denom = 0.f;
#pragma unroll
      for (int w2 = 0; w2 < 4; ++w2)
        denom += Sl[w2][row] * __expf(Sm[w2][row] - M);
      Dinv[row] = 1.0f / denom;
    }
  }
  __syncthreads();
  const int t = threadIdx.x;
#pragma unroll
  for (int k2 = 0; k2 < 4; ++k2) {
    const int e = t + 256 * k2;
    const int row = e >> 6, col = e & 63;
    const float s = OB[0][row][col] + OB[1][row][col] + OB[2][row][col] +
                    OB[3][row][col];
    out[((size_t)b * TT + q0 + row) * 64 + col] = s * Dinv[row];
  }
}

// ------------------------------------------------------------------ launch ---
extern "C" void kernel_launch(void* const* d_in, const int* in_sizes, int n_in,
                              void* d_out, int out_size, void* d_ws,
                              size_t ws_size, hipStream_t stream) {
  const float* x = (const float*)d_in[0];
  const float* Wq = (const float*)d_in[1];
  const float* Wk = (const float*)d_in[2];
  const float* Wv = (const float*)d_in[3];
  float* out = (float*)d_out;
  char* ws = (char*)d_ws;

  size_t off = 0;
  __bf16* WC = (__bf16*)(ws + off); off += (size_t)8 * WSLICE * 2;  // 655KB
  __bf16* qh = (__bf16*)(ws + off); off += (size_t)NROW * 64 * 2;
  __bf16* ql = (__bf16*)(ws + off); off += (size_t)NROW * 64 * 2;
  __bf16* kh = (__bf16*)(ws + off); off += (size_t)NROW * 64 * 2;
  __bf16* kl = (__bf16*)(ws + off); off += (size_t)NROW * 64 * 2;
  __bf16* vt = (__bf16*)(ws + off); off += (size_t)NROW * 64 * 2;  // ~11.1 MB

  wprep_kernel<<<dim3(32), dim3(256), 0, stream>>>(Wq, Wk, Wv, WC);
  proj_kernel<<<dim3(512), dim3(512), 0, stream>>>(
      x, WC, qh, ql, kh, kl, vt);
  attn_kernel<<<dim3(1024), dim3(256), 0, stream>>>(
      qh, ql, kh, kl, vt, out);
}